// Round 12
// baseline (1019.216 us; speedup 1.0000x reference)
//
#include <hip/hip_runtime.h>
#include <hip/hip_bf16.h>

typedef unsigned short ushortt;
typedef __attribute__((ext_vector_type(8))) short short8v;
typedef __attribute__((ext_vector_type(4))) float f32x4;

#define H_ 32
#define W_ 32
#define C_ 3
#define PH_ 5
#define PW_ 5
#define HP_ 28
#define WP_ 28
#define P_ 784
#define N_ 32
#define L_ 75
#define LP_ 80            /* padded L for float4 staging */
#define G_ 2
#define M_ 384
#define MM_ (M_*M_)       /* 147456 */
#define PN_ (P_*N_)       /* 25088 */
#define JITTER_ 1e-6

__device__ __forceinline__ float bf2f(ushortt u) {
  return __uint_as_float(((unsigned int)u) << 16);
}
__device__ __forceinline__ ushortt f2bf(float f) {
  __hip_bfloat16 h = __float2bfloat16(f);
  ushortt u;
  __builtin_memcpy(&u, &h, sizeof(u));
  return u;
}

// accurate exp(t) for t <= 0, fp64
__device__ __forceinline__ double exp64(double t) {
  double y = t * 1.4426950408889634;
  double nn = rint(y);
  double z = (y - nn) * 0.6931471805599453;
  double e = 1.6059043836821613e-10;
  e = fma(e, z, 2.08767569878681e-9);
  e = fma(e, z, 2.505210838544172e-8);
  e = fma(e, z, 2.755731922398589e-7);
  e = fma(e, z, 2.7557319223985893e-6);
  e = fma(e, z, 2.48015873015873e-5);
  e = fma(e, z, 1.984126984126984e-4);
  e = fma(e, z, 1.3888888888888889e-3);
  e = fma(e, z, 8.333333333333333e-3);
  e = fma(e, z, 4.1666666666666664e-2);
  e = fma(e, z, 1.6666666666666666e-1);
  e = fma(e, z, 0.5);
  e = fma(e, z, 1.0);
  e = fma(e, z, 1.0);
  return ldexp(e, (int)nn);
}

// ---------------- fused prep: Zt transpose + znorm + output init ----------------
__global__ void k_prep1(const float* __restrict__ Z, float* __restrict__ Zt,
                        float* __restrict__ znorm, float* __restrict__ outp,
                        const float* vptr) {
  int idx = blockIdx.x * 256 + threadIdx.x;
  if (idx < G_ * L_ * M_) {
    int m = idx % M_;
    int l = (idx / M_) % L_;
    int g = idx / (M_ * L_);
    Zt[idx] = Z[(g * M_ + m) * L_ + l];
  }
  if (idx < G_ * M_) {
    const float* zr = Z + (size_t)idx * L_;
    float s = 0.f;
    for (int l = 0; l < L_; ++l) s = fmaf(zr[l], zr[l], s);
    znorm[idx] = s;
  }
  if (idx < PN_ * G_) {
    outp[idx] = 0.f;
    outp[PN_ * G_ + idx] = vptr[0];
  }
}

// ---------------- fused patches + pnorm: 256-thread blocks, one wave per x ----------------
__global__ __launch_bounds__(256) void k_patchnorm(const float* __restrict__ xin,
                                                   float* __restrict__ pat,
                                                   float* __restrict__ pnorm) {
  int wv = threadIdx.x >> 6;
  int t = threadIdx.x & 63;
  int x = blockIdx.x * 4 + wv;
  int n = x & 31, p = x >> 5;
  int hp = p / WP_, wp = p % WP_;
  const float* xb = xin + n * (H_ * W_ * C_);
  auto pval = [&](int l) -> float {
    if (l >= L_) return 0.f;
    int q = l / C_, c = l % C_;
    int i = q / PW_, j = q % PW_;
    return xb[((hp + i) * W_ + (wp + j)) * C_ + c];
  };
  float v1 = pval(t);
  float v2 = (t < 16) ? pval(t + 64) : 0.f;
  pat[(size_t)x * LP_ + t] = v1;
  if (t < 16) pat[(size_t)x * LP_ + 64 + t] = v2;
  float s = v1 * v1 + v2 * v2;
#pragma unroll
  for (int off = 32; off; off >>= 1) s += __shfl_down(s, off);
  if (t == 0) pnorm[x] = s;
}

// ---------------- Kuu fp64 + fp32 copy ----------------
__global__ void k_kuu64(const float* __restrict__ Z, const float* vptr,
                        const float* lptr, double* __restrict__ Kuu64,
                        float* __restrict__ Kuu32) {
  int idx = blockIdx.x * 256 + threadIdx.x;
  if (idx >= G_ * MM_) return;
  int j = idx % M_;
  int r = (idx / M_) % M_;
  int g = idx / MM_;
  const float* zi = Z + (g * M_ + r) * L_;
  const float* zj = Z + (g * M_ + j) * L_;
  double s = 0.0;
  for (int l = 0; l < L_; ++l) {
    double d = (double)zi[l] - (double)zj[l];
    s = fma(d, d, s);
  }
  double v = (double)vptr[0], ls = (double)lptr[0];
  double val = v * exp64(-0.5 * s / (ls * ls));
  if (r == j) val += JITTER_;
  Kuu64[idx] = val;
  Kuu32[idx] = (float)val;
}

// ---------------- 192x192 Gauss-Jordan inverse, 1 barrier/iter (verified) ----------------
__global__ __launch_bounds__(512) void k_inv192(const float* __restrict__ in,
                                                float* __restrict__ out, int gstride) {
  int g = blockIdx.x;
  const float* A = in + (size_t)g * gstride;
  float* O = out + (size_t)g * gstride;
  int t = threadIdx.x;
  int ti = t >> 4, tj = t & 15;
  float a[6][12];
#pragma unroll
  for (int i2 = 0; i2 < 6; ++i2)
#pragma unroll
    for (int j2 = 0; j2 < 12; ++j2)
      a[i2][j2] = A[(ti + 32 * i2) * M_ + (tj + 16 * j2)];

  __shared__ float rowb[2][192], colb[2][192];
  if (ti == 0) {
#pragma unroll
    for (int j2 = 0; j2 < 12; ++j2) rowb[0][tj + 16 * j2] = a[0][j2];
  }
  if (tj == 0) {
#pragma unroll
    for (int i2 = 0; i2 < 6; ++i2) colb[0][ti + 32 * i2] = a[i2][0];
  }
  __syncthreads();

#pragma unroll
  for (int i2k = 0; i2k < 6; ++i2k) {
#pragma unroll
    for (int kh = 0; kh < 2; ++kh) {
      const int j2k = i2k * 2 + kh;
      for (int k2 = 0; k2 < 16; ++k2) {
        const int k = i2k * 32 + kh * 16 + k2;
        const int cur = k & 1, nxt = cur ^ 1;
        const int krow = kh * 16 + k2;
        float p = 1.0f / rowb[cur][k];
        float rv[12];
#pragma unroll
        for (int j2 = 0; j2 < 12; ++j2) rv[j2] = rowb[cur][tj + 16 * j2] * p;
        float cvl[6];
#pragma unroll
        for (int i2 = 0; i2 < 6; ++i2) cvl[i2] = colb[cur][ti + 32 * i2];

        if (k2 < 15) {
          if (ti == krow + 1) {
#pragma unroll
            for (int j2 = 0; j2 < 12; ++j2) {
              float tv = fmaf(-cvl[i2k], rv[j2], a[i2k][j2]);
              if (tj == k2 && j2 == j2k) tv = -cvl[i2k] * p;
              rowb[nxt][tj + 16 * j2] = tv;
            }
          }
          if (tj == k2 + 1) {
#pragma unroll
            for (int i2 = 0; i2 < 6; ++i2) {
              float tv = fmaf(-cvl[i2], rv[j2k], a[i2][j2k]);
              if (ti == krow && i2 == i2k) tv = rv[j2k];
              colb[nxt][ti + 32 * i2] = tv;
            }
          }
        } else if (!(i2k == 5 && kh == 1)) {
          const int i2k1 = (kh == 0) ? i2k : i2k + 1;
          const int krow1 = (kh == 0) ? 16 : 0;
          const int j2k1 = j2k + 1;
          if (ti == krow1) {
#pragma unroll
            for (int j2 = 0; j2 < 12; ++j2) {
              float tv = fmaf(-cvl[i2k1], rv[j2], a[i2k1][j2]);
              if (tj == 15 && j2 == j2k) tv = -cvl[i2k1] * p;
              rowb[nxt][tj + 16 * j2] = tv;
            }
          }
          if (tj == 0) {
#pragma unroll
            for (int i2 = 0; i2 < 6; ++i2) {
              float tv = fmaf(-cvl[i2], rv[j2k1], a[i2][j2k1]);
              if (ti == krow && i2 == i2k) tv = rv[j2k1];
              colb[nxt][ti + 32 * i2] = tv;
            }
          }
        }
        __syncthreads();

#pragma unroll
        for (int i2 = 0; i2 < 6; ++i2)
#pragma unroll
          for (int j2 = 0; j2 < 12; ++j2)
            a[i2][j2] = fmaf(-cvl[i2], rv[j2], a[i2][j2]);
        if (ti == krow) {
#pragma unroll
          for (int j2 = 0; j2 < 12; ++j2) a[i2k][j2] = rv[j2];
        }
        if (tj == k2) {
#pragma unroll
          for (int i2 = 0; i2 < 6; ++i2) a[i2][j2k] = -cvl[i2] * p;
        }
        if (ti == krow && tj == k2) a[i2k][j2k] = p;
      }
    }
  }
#pragma unroll
  for (int i2 = 0; i2 < 6; ++i2)
#pragma unroll
    for (int j2 = 0; j2 < 12; ++j2)
      O[(ti + 32 * i2) * M_ + (tj + 16 * j2)] = a[i2][j2];
}

// ---------------- fp32 tiled GEMM (Schur chain) ----------------
__global__ __launch_bounds__(256) void k_sgemm(
    const float* __restrict__ A, int lda, int tA, int sAg,
    const float* __restrict__ B, int ldb, int tB, int sBg,
    const float* __restrict__ Cin, int sCing, float beta,
    float alpha, int addI,
    float* __restrict__ Cout, int ldc, int sCg,
    float* __restrict__ CoutT, int ldt, int sTg,
    int M, int N, int K) {
  int g = blockIdx.z;
  A += (size_t)g * sAg;
  B += (size_t)g * sBg;
  if (Cin) Cin += (size_t)g * sCing;
  Cout += (size_t)g * sCg;
  if (CoutT) CoutT += (size_t)g * sTg;

  __shared__ float As[32][33], Bs[32][33];
  int t = threadIdx.x;
  int tx = t & 15, ty = t >> 4;
  int row0 = blockIdx.y * 32, col0 = blockIdx.x * 32;
  float acc00 = 0.f, acc01 = 0.f, acc10 = 0.f, acc11 = 0.f;

  for (int kt = 0; kt < K; kt += 32) {
    for (int idx = t; idx < 1024; idx += 256) {
      int rr = idx >> 5, cc = idx & 31;
      {
        int gr = row0 + rr, gk = kt + cc;
        As[rr][cc] = tA ? A[(size_t)gk * lda + gr] : A[(size_t)gr * lda + gk];
      }
      {
        int gk = kt + rr, gc = col0 + cc;
        Bs[rr][cc] = tB ? B[(size_t)gc * ldb + gk] : B[(size_t)gk * ldb + gc];
      }
    }
    __syncthreads();
#pragma unroll
    for (int kk = 0; kk < 32; ++kk) {
      float a0 = As[ty * 2][kk], a1 = As[ty * 2 + 1][kk];
      float b0 = Bs[kk][tx * 2], b1 = Bs[kk][tx * 2 + 1];
      acc00 = fmaf(a0, b0, acc00);
      acc01 = fmaf(a0, b1, acc01);
      acc10 = fmaf(a1, b0, acc10);
      acc11 = fmaf(a1, b1, acc11);
    }
    __syncthreads();
  }
  float accs[2][2] = {{acc00, acc01}, {acc10, acc11}};
#pragma unroll
  for (int a2 = 0; a2 < 2; ++a2)
#pragma unroll
    for (int b2 = 0; b2 < 2; ++b2) {
      int gr = row0 + ty * 2 + a2, gc = col0 + tx * 2 + b2;
      float val = alpha * accs[a2][b2];
      if (addI && gr == gc) val += 1.0f;
      if (Cin) val += beta * Cin[(size_t)gr * ldc + gc];
      Cout[(size_t)gr * ldc + gc] = val;
      if (CoutT) CoutT[(size_t)gc * ldt + gr] = val;
    }
}

// ---------------- mixed-precision fp64-accum GEMM ----------------
__global__ __launch_bounds__(256) void k_dgemmx(
    const void* __restrict__ Ap, int aF64, int lda, int tA, size_t sAg,
    const void* __restrict__ Bp, int bF64, int ldb, int tB, int btril, size_t sBg,
    const void* __restrict__ Cp, int cF64, size_t sCing, double beta,
    double alpha, int addI,
    double* __restrict__ Cout, int ldc, size_t sCg,
    float* __restrict__ f32out,
    int M, int N, int K) {
  int g = blockIdx.z;
  const double* A64 = (const double*)Ap + (size_t)g * sAg;
  const float* A32 = (const float*)Ap + (size_t)g * sAg;
  const double* B64 = (const double*)Bp + (size_t)g * sBg;
  const float* B32 = (const float*)Bp + (size_t)g * sBg;
  const double* C64 = Cp ? (const double*)Cp + (size_t)g * sCing : nullptr;
  const float* C32 = Cp ? (const float*)Cp + (size_t)g * sCing : nullptr;
  if (Cout) Cout += (size_t)g * sCg;
  if (f32out) f32out += (size_t)g * sCg;

  __shared__ double As[32][33], Bs[32][33];
  int t = threadIdx.x;
  int tx = t & 15, ty = t >> 4;
  int row0 = blockIdx.y * 32, col0 = blockIdx.x * 32;
  double acc00 = 0., acc01 = 0., acc10 = 0., acc11 = 0.;

  for (int kt = 0; kt < K; kt += 32) {
    for (int idx = t; idx < 1024; idx += 256) {
      int rr = idx >> 5, cc = idx & 31;
      {
        int gr = row0 + rr, gk = kt + cc;
        size_t ai = tA ? ((size_t)gk * lda + gr) : ((size_t)gr * lda + gk);
        As[rr][cc] = aF64 ? A64[ai] : (double)A32[ai];
      }
      {
        int gk = kt + rr, gc = col0 + cc;
        size_t bi = tB ? ((size_t)gc * ldb + gk) : ((size_t)gk * ldb + gc);
        double bv = bF64 ? B64[bi] : (double)B32[bi];
        if (btril && gc > gk) bv = 0.0;
        Bs[rr][cc] = bv;
      }
    }
    __syncthreads();
#pragma unroll
    for (int kk = 0; kk < 32; ++kk) {
      double a0 = As[ty * 2][kk], a1 = As[ty * 2 + 1][kk];
      double b0 = Bs[kk][tx * 2], b1 = Bs[kk][tx * 2 + 1];
      acc00 = fma(a0, b0, acc00);
      acc01 = fma(a0, b1, acc01);
      acc10 = fma(a1, b0, acc10);
      acc11 = fma(a1, b1, acc11);
    }
    __syncthreads();
  }
  double accs[2][2] = {{acc00, acc01}, {acc10, acc11}};
#pragma unroll
  for (int a2 = 0; a2 < 2; ++a2)
#pragma unroll
    for (int b2 = 0; b2 < 2; ++b2) {
      int gr = row0 + ty * 2 + a2, gc = col0 + tx * 2 + b2;
      double val = alpha * accs[a2][b2];
      if (addI && gr == gc) val += 1.0;
      if (C64) {
        double cv = cF64 ? C64[(size_t)gr * ldc + gc] : (double)C32[(size_t)gr * ldc + gc];
        val += beta * cv;
      }
      if (Cout) Cout[(size_t)gr * ldc + gc] = val;
      if (f32out) f32out[(size_t)gr * ldc + gc] = (float)val;
    }
}

// ---------------- c_g = X * q_mu[:,g] ----------------
__global__ void k_cvec64(const double* __restrict__ X, const float* __restrict__ qmu,
                         float* __restrict__ cvec) {
  int idx = blockIdx.x * 256 + threadIdx.x;
  if (idx >= G_ * M_) return;
  int m = idx % M_, g = idx / M_;
  const double* row = X + (size_t)g * MM_ + (size_t)m * M_;
  double s = 0.0;
  for (int k = 0; k < M_; ++k) s = fma(row[k], (double)qmu[k * G_ + g], s);
  cvec[idx] = (float)s;
}

// ---------------- split S into bf16 hi/lo ----------------
__global__ void k_splitS(const float* __restrict__ Sf, ushortt* __restrict__ Shi,
                         ushortt* __restrict__ Slo) {
  int idx = blockIdx.x * 256 + threadIdx.x;
  if (idx >= G_ * MM_) return;
  float s = Sf[idx];
  ushortt h = f2bf(s);
  Shi[idx] = h;
  Slo[idx] = f2bf(s - bf2f(h));
}

// ---------------- Kuf as GEMM (64x64 tile) -> Kx fp32 + Khi/Klo bf16 ----------------
__global__ __launch_bounds__(256) void k_kufg(const float* __restrict__ pat,
                                              const float* __restrict__ Zt,
                                              const float* __restrict__ znorm,
                                              const float* __restrict__ pnorm,
                                              const float* vptr, const float* lptr,
                                              float* __restrict__ Kx,
                                              ushortt* __restrict__ Khi,
                                              ushortt* __restrict__ Klo,
                                              int x0, int chx) {
  int g = blockIdx.z;
  int col0 = blockIdx.x * 64;
  int row0 = blockIdx.y * 64;
  __shared__ __align__(16) float As[16][68];
  __shared__ __align__(16) float Bs[16][68];
  int t = threadIdx.x;
  int tr = t >> 4, tc = t & 15;
  float acc[4][4] = {};

  for (int kt = 0; kt < LP_; kt += 16) {
    {
      int r = t >> 2, k4 = (t & 3) * 4;
      float4 av = *(const float4*)&pat[(size_t)(x0 + row0 + r) * LP_ + kt + k4];
      As[k4 + 0][r] = av.x;
      As[k4 + 1][r] = av.y;
      As[k4 + 2][r] = av.z;
      As[k4 + 3][r] = av.w;
    }
    {
      int k = t >> 4, c4 = (t & 15) * 4;
      float4 bv = {0.f, 0.f, 0.f, 0.f};
      if (kt + k < L_)
        bv = *(const float4*)&Zt[((size_t)(g * L_ + kt + k)) * M_ + col0 + c4];
      *(float4*)&Bs[k][c4] = bv;
    }
    __syncthreads();
#pragma unroll
    for (int k = 0; k < 16; ++k) {
      float4 av = *(const float4*)&As[k][tr * 4];
      float4 bv = *(const float4*)&Bs[k][tc * 4];
      float a4[4] = {av.x, av.y, av.z, av.w};
      float b4[4] = {bv.x, bv.y, bv.z, bv.w};
#pragma unroll
      for (int i = 0; i < 4; ++i)
#pragma unroll
        for (int j = 0; j < 4; ++j) acc[i][j] = fmaf(a4[i], b4[j], acc[i][j]);
    }
    __syncthreads();
  }
  float v = vptr[0], ls = lptr[0];
  float c2 = -0.72134752044f / (ls * ls);
#pragma unroll
  for (int i = 0; i < 4; ++i) {
    int xl = row0 + tr * 4 + i;
    float pn = pnorm[x0 + xl];
    float tmp[4];
    ushortt hi[4], lo[4];
#pragma unroll
    for (int j = 0; j < 4; ++j) {
      int m = col0 + tc * 4 + j;
      float sq = znorm[g * M_ + m] + pn - 2.0f * acc[i][j];
      tmp[j] = v * exp2f(sq * c2);
      hi[j] = f2bf(tmp[j]);
      lo[j] = f2bf(tmp[j] - bf2f(hi[j]));
    }
    size_t base = ((size_t)g * chx + xl) * M_ + col0 + tc * 4;
    float4 ov = {tmp[0], tmp[1], tmp[2], tmp[3]};
    *(float4*)&Kx[base] = ov;
    *(ushort4*)&Khi[base] = make_ushort4(hi[0], hi[1], hi[2], hi[3]);
    *(ushort4*)&Klo[base] = make_ushort4(lo[0], lo[1], lo[2], lo[3]);
  }
}

// ---------------- MFMA U-GEMM + fold, full-M per block ----------------
// Block 256 = 4 waves; tile 64 rows(x) x 384 cols (24 col-tiles of 16).
// Each K row read ONCE. U = Khi*Shi + Khi*Slo + Klo*Shi (lo*lo dropped, ~2^-18).
// A frag: A[m=lane&15][k=q*8+j]; B frag uses S symmetry: S[n][kb..] contiguous.
// C: col=lane&15, row=q*4+reg. One block covers a row's full M -> direct stores.
__global__ __launch_bounds__(256) void k_ufoldm(
    const ushortt* __restrict__ Khi, const ushortt* __restrict__ Klo,
    const float* __restrict__ Kx32,
    const ushortt* __restrict__ Shi, const ushortt* __restrict__ Slo,
    const float* __restrict__ cvec, const float* vptr,
    float* __restrict__ outp, int x0, int chx) {
  int g = blockIdx.y;
  int row0 = blockIdx.x * 64;
  const ushortt* Ah = Khi + (size_t)g * chx * M_;
  const ushortt* Al = Klo + (size_t)g * chx * M_;
  const float* A32 = Kx32 + (size_t)g * chx * M_;
  const ushortt* Bh = Shi + (size_t)g * MM_;
  const ushortt* Bl = Slo + (size_t)g * MM_;

  __shared__ float cs[M_];
  int t = threadIdx.x;
  cs[t] = cvec[g * M_ + t];
  if (t < M_ - 256) cs[256 + t] = cvec[g * M_ + 256 + t];
  __syncthreads();

  int w = t >> 6;
  int lane = t & 63;
  int n15 = lane & 15;
  int q = lane >> 4;
  int xr = row0 + w * 16 + n15;

  f32x4 acc[24];
#pragma unroll
  for (int ct = 0; ct < 24; ++ct) acc[ct] = (f32x4){0.f, 0.f, 0.f, 0.f};

  for (int kt = 0; kt < M_; kt += 32) {
    int kb = kt + q * 8;
    short8v ahi = *(const short8v*)&Ah[(size_t)xr * M_ + kb];
    short8v alo = *(const short8v*)&Al[(size_t)xr * M_ + kb];
#pragma unroll
    for (int ct = 0; ct < 24; ++ct) {
      int nn = ct * 16 + n15;
      short8v bhi = *(const short8v*)&Bh[(size_t)nn * M_ + kb];
      short8v blo = *(const short8v*)&Bl[(size_t)nn * M_ + kb];
      acc[ct] = __builtin_amdgcn_mfma_f32_16x16x32_bf16(ahi, bhi, acc[ct], 0, 0, 0);
      acc[ct] = __builtin_amdgcn_mfma_f32_16x16x32_bf16(ahi, blo, acc[ct], 0, 0, 0);
      acc[ct] = __builtin_amdgcn_mfma_f32_16x16x32_bf16(alo, bhi, acc[ct], 0, 0, 0);
    }
  }

  // fold: complete over all M -> direct store. fp32 exact k (Kx32), fp64 partials.
  float v = vptr[0];
#pragma unroll
  for (int reg = 0; reg < 4; ++reg) {
    int xr2 = row0 + w * 16 + q * 4 + reg;
    const float* arow = &A32[(size_t)xr2 * M_];
    double pv = 0.0, pm = 0.0;
#pragma unroll
    for (int ct = 0; ct < 24; ++ct) {
      int col = ct * 16 + n15;
      float kval = arow[col];
      pv += (double)kval * acc[ct][reg];
      pm += (double)kval * cs[col];
    }
#pragma unroll
    for (int mk = 1; mk < 16; mk <<= 1) {
      pv += __shfl_xor(pv, mk, 16);
      pm += __shfl_xor(pm, mk, 16);
    }
    if (n15 == 0) {
      int x = x0 + xr2;
      int p = x >> 5, n = x & 31;
      int oidx = n * (P_ * G_) + p * G_ + g;
      outp[oidx] = (float)pm;
      outp[PN_ * G_ + oidx] = v + (float)pv;
    }
  }
}

extern "C" void kernel_launch(void* const* d_in, const int* in_sizes, int n_in,
                              void* d_out, int out_size, void* d_ws, size_t ws_size,
                              hipStream_t stream) {
  (void)out_size;
  const float* xin = (const float*)d_in[0];
  const float* Z = (const float*)d_in[1];
  const float* qmu = (const float*)d_in[2];
  const float* qsqrt = (const float*)d_in[3];
  const float* vptr = (const float*)d_in[4];
  const float* lptr = (const float*)d_in[5];
  {
    int scalars = 0;
    for (int i = 0; i < n_in; ++i) {
      if (in_sizes[i] == N_ * H_ * W_ * C_) xin = (const float*)d_in[i];
      else if (in_sizes[i] == G_ * M_ * L_) Z = (const float*)d_in[i];
      else if (in_sizes[i] == M_ * G_) qmu = (const float*)d_in[i];
      else if (in_sizes[i] == G_ * MM_) qsqrt = (const float*)d_in[i];
      else if (in_sizes[i] == 1) {
        if (scalars == 0) vptr = (const float*)d_in[i];
        else lptr = (const float*)d_in[i];
        ++scalars;
      }
    }
  }
  float* outp = (float*)d_out;

  auto align256 = [](size_t b) { return (b + 255) & ~(size_t)255; };
  size_t fixed = 0;
  fixed += align256((size_t)G_ * L_ * M_ * 4);      // Zt
  fixed += align256((size_t)G_ * M_ * 4);           // znorm
  fixed += align256((size_t)PN_ * LP_ * 4);         // pat
  fixed += align256((size_t)PN_ * 4);               // pnorm
  fixed += align256((size_t)G_ * MM_ * 4) * 2;      // Kuu32, Kinv32
  fixed += align256((size_t)G_ * 192 * 192 * 4);    // Ebuf
  fixed += align256((size_t)G_ * MM_ * 8) * 3;      // Kuu64, Xd2, Rd
  fixed += align256((size_t)G_ * MM_ * 4);          // Sf
  fixed += align256((size_t)G_ * MM_ * 2) * 2;      // Shi, Slo
  fixed += align256((size_t)G_ * M_ * 4);           // cvec
  size_t kfam = (size_t)G_ * PN_ * M_ * 8;          // Kx fp32 + Khi + Klo per full span
  int nc = 4;
  if (ws_size >= fixed + align256(kfam) + (1u << 20)) nc = 1;
  else if (ws_size >= fixed + align256(kfam / 2) + (1u << 20)) nc = 2;
  int chx = PN_ / nc;   // divisible by 64 for nc in {1,2,4}

  char* w = (char*)d_ws;
  auto alloc = [&](size_t bytes) {
    char* r = w;
    w += (bytes + 255) & ~(size_t)255;
    return r;
  };
  float* Zt      = (float*)alloc((size_t)G_ * L_ * M_ * 4);
  float* znorm   = (float*)alloc((size_t)G_ * M_ * 4);
  float* pat     = (float*)alloc((size_t)PN_ * LP_ * 4);
  float* pnorm   = (float*)alloc((size_t)PN_ * 4);
  float* Kuu32   = (float*)alloc((size_t)G_ * MM_ * 4);
  float* Kinv32  = (float*)alloc((size_t)G_ * MM_ * 4);
  float* Ebuf    = (float*)alloc((size_t)G_ * 192 * 192 * 4);
  double* Kuu64  = (double*)alloc((size_t)G_ * MM_ * 8);
  double* Xd2    = (double*)alloc((size_t)G_ * MM_ * 8);
  double* Rd     = (double*)alloc((size_t)G_ * MM_ * 8);
  float* Sf      = (float*)alloc((size_t)G_ * MM_ * 4);
  ushortt* Shi   = (ushortt*)alloc((size_t)G_ * MM_ * 2);
  ushortt* Slo   = (ushortt*)alloc((size_t)G_ * MM_ * 2);
  float* cvec    = (float*)alloc((size_t)G_ * M_ * 4);
  float* Kx      = (float*)alloc((size_t)G_ * chx * M_ * 4);
  ushortt* Khi   = (ushortt*)alloc((size_t)G_ * chx * M_ * 2);
  ushortt* Klo   = (ushortt*)alloc((size_t)G_ * chx * M_ * 2);

  // ---- prep ----
  k_prep1<<<(G_ * L_ * M_ + 255) / 256, 256, 0, stream>>>(Z, Zt, znorm, outp, vptr);
  k_patchnorm<<<PN_ / 4, 256, 0, stream>>>(xin, pat, pnorm);
  k_kuu64<<<(G_ * MM_ + 255) / 256, 256, 0, stream>>>(Z, vptr, lptr, Kuu64, Kuu32);

  // ---- fp32 seed: Kinv32 via 2x2 block Schur (192+192) ----
  k_inv192<<<G_, 512, 0, stream>>>(Kuu32, Kinv32, MM_);
  k_sgemm<<<dim3(6, 6, G_), 256, 0, stream>>>(
      Kinv32, M_, 0, MM_, Kuu32 + 192, M_, 0, MM_,
      nullptr, 0, 0.0f, 1.0f, 0,
      Ebuf, 192, 192 * 192, nullptr, 0, 0, 192, 192, 192);
  k_sgemm<<<dim3(6, 6, G_), 256, 0, stream>>>(
      Kuu32 + 192, M_, 1, MM_, Ebuf, 192, 0, 192 * 192,
      Kuu32 + 192 * M_ + 192, MM_, 1.0f, -1.0f, 0,
      Kuu32 + 192 * M_ + 192, M_, MM_, nullptr, 0, 0, 192, 192, 192);
  k_inv192<<<G_, 512, 0, stream>>>(Kuu32 + 192 * M_ + 192, Kinv32 + 192 * M_ + 192, MM_);
  k_sgemm<<<dim3(6, 6, G_), 256, 0, stream>>>(
      Ebuf, 192, 0, 192 * 192, Kinv32 + 192 * M_ + 192, M_, 0, MM_,
      nullptr, 0, 0.0f, -1.0f, 0,
      Kinv32 + 192, M_, MM_, Kinv32 + 192 * M_, M_, MM_, 192, 192, 192);
  k_sgemm<<<dim3(6, 6, G_), 256, 0, stream>>>(
      Kinv32 + 192, M_, 0, MM_, Ebuf, 192, 1, 192 * 192,
      Kinv32, MM_, 1.0f, -1.0f, 0,
      Kinv32, M_, MM_, nullptr, 0, 0, 192, 192, 192);

  // ---- one fp64 Newton step: X2 = X0 + X0(I - Kuu X0) ----
  k_dgemmx<<<dim3(12, 12, G_), 256, 0, stream>>>(
      Kuu64, 1, M_, 0, (size_t)MM_,
      Kinv32, 0, M_, 0, 0, (size_t)MM_,
      nullptr, 0, 0, 0.0,
      -1.0, 1, Rd, M_, (size_t)MM_, nullptr, M_, M_, M_);
  k_dgemmx<<<dim3(12, 12, G_), 256, 0, stream>>>(
      Kinv32, 0, M_, 0, (size_t)MM_,
      Rd, 1, M_, 0, 0, (size_t)MM_,
      Kinv32, 0, (size_t)MM_, 1.0,
      1.0, 0, Xd2, M_, (size_t)MM_, nullptr, M_, M_, M_);

  // ---- S = (X Lq)(X Lq)^T - X -> Sf fp32 -> bf16 hi/lo ; c = X q_mu ----
  k_dgemmx<<<dim3(12, 12, G_), 256, 0, stream>>>(
      Xd2, 1, M_, 0, (size_t)MM_,
      qsqrt, 0, M_, 0, 1, (size_t)MM_,
      nullptr, 0, 0, 0.0,
      1.0, 0, Rd, M_, (size_t)MM_, nullptr, M_, M_, M_);      // Rd = V
  k_dgemmx<<<dim3(12, 12, G_), 256, 0, stream>>>(
      Rd, 1, M_, 0, (size_t)MM_,
      Rd, 1, M_, 1, 0, (size_t)MM_,
      Xd2, 1, (size_t)MM_, -1.0,
      1.0, 0, nullptr, M_, (size_t)MM_, Sf, M_, M_, M_);       // Sf = V V^T - X
  k_splitS<<<(G_ * MM_ + 255) / 256, 256, 0, stream>>>(Sf, Shi, Slo);
  k_cvec64<<<(G_ * M_ + 255) / 256, 256, 0, stream>>>(Xd2, qmu, cvec);

  // ---- per-chunk: K build (fp32 + bf16 hi/lo), MFMA U-GEMM + fold ----
  for (int ch = 0; ch < nc; ++ch) {
    int x0 = ch * chx;
    k_kufg<<<dim3(M_ / 64, chx / 64, G_), 256, 0, stream>>>(
        pat, Zt, znorm, pnorm, vptr, lptr, Kx, Khi, Klo, x0, chx);
    k_ufoldm<<<dim3(chx / 64, G_), 256, 0, stream>>>(
        Khi, Klo, Kx, Shi, Slo, cvec, vptr, outp, x0, chx);
  }
}

// Round 13
// 770.905 us; speedup vs baseline: 1.3221x; 1.3221x over previous
//
#include <hip/hip_runtime.h>
#include <hip/hip_bf16.h>

typedef unsigned short ushortt;
typedef __attribute__((ext_vector_type(8))) short short8v;
typedef __attribute__((ext_vector_type(4))) float f32x4;

#define H_ 32
#define W_ 32
#define C_ 3
#define PH_ 5
#define PW_ 5
#define HP_ 28
#define WP_ 28
#define P_ 784
#define N_ 32
#define L_ 75
#define LP_ 80            /* padded L for float4 staging */
#define G_ 2
#define M_ 384
#define MM_ (M_*M_)       /* 147456 */
#define PN_ (P_*N_)       /* 25088 */
#define JITTER_ 1e-6

__device__ __forceinline__ float bf2f(ushortt u) {
  return __uint_as_float(((unsigned int)u) << 16);
}
__device__ __forceinline__ ushortt f2bf(float f) {
  __hip_bfloat16 h = __float2bfloat16(f);
  ushortt u;
  __builtin_memcpy(&u, &h, sizeof(u));
  return u;
}

// accurate exp(t) for t <= 0, fp64
__device__ __forceinline__ double exp64(double t) {
  double y = t * 1.4426950408889634;
  double nn = rint(y);
  double z = (y - nn) * 0.6931471805599453;
  double e = 1.6059043836821613e-10;
  e = fma(e, z, 2.08767569878681e-9);
  e = fma(e, z, 2.505210838544172e-8);
  e = fma(e, z, 2.755731922398589e-7);
  e = fma(e, z, 2.7557319223985893e-6);
  e = fma(e, z, 2.48015873015873e-5);
  e = fma(e, z, 1.984126984126984e-4);
  e = fma(e, z, 1.3888888888888889e-3);
  e = fma(e, z, 8.333333333333333e-3);
  e = fma(e, z, 4.1666666666666664e-2);
  e = fma(e, z, 1.6666666666666666e-1);
  e = fma(e, z, 0.5);
  e = fma(e, z, 1.0);
  e = fma(e, z, 1.0);
  return ldexp(e, (int)nn);
}

// ---------------- fused prep: Zt transpose + znorm + output init ----------------
__global__ void k_prep1(const float* __restrict__ Z, float* __restrict__ Zt,
                        float* __restrict__ znorm, float* __restrict__ outp,
                        const float* vptr) {
  int idx = blockIdx.x * 256 + threadIdx.x;
  if (idx < G_ * L_ * M_) {
    int m = idx % M_;
    int l = (idx / M_) % L_;
    int g = idx / (M_ * L_);
    Zt[idx] = Z[(g * M_ + m) * L_ + l];
  }
  if (idx < G_ * M_) {
    const float* zr = Z + (size_t)idx * L_;
    float s = 0.f;
    for (int l = 0; l < L_; ++l) s = fmaf(zr[l], zr[l], s);
    znorm[idx] = s;
  }
  if (idx < PN_ * G_) {
    outp[idx] = 0.f;
    outp[PN_ * G_ + idx] = vptr[0];
  }
}

// ---------------- fused patches + pnorm: 256-thread blocks, one wave per x ----------------
__global__ __launch_bounds__(256) void k_patchnorm(const float* __restrict__ xin,
                                                   float* __restrict__ pat,
                                                   float* __restrict__ pnorm) {
  int wv = threadIdx.x >> 6;
  int t = threadIdx.x & 63;
  int x = blockIdx.x * 4 + wv;
  int n = x & 31, p = x >> 5;
  int hp = p / WP_, wp = p % WP_;
  const float* xb = xin + n * (H_ * W_ * C_);
  auto pval = [&](int l) -> float {
    if (l >= L_) return 0.f;
    int q = l / C_, c = l % C_;
    int i = q / PW_, j = q % PW_;
    return xb[((hp + i) * W_ + (wp + j)) * C_ + c];
  };
  float v1 = pval(t);
  float v2 = (t < 16) ? pval(t + 64) : 0.f;
  pat[(size_t)x * LP_ + t] = v1;
  if (t < 16) pat[(size_t)x * LP_ + 64 + t] = v2;
  float s = v1 * v1 + v2 * v2;
#pragma unroll
  for (int off = 32; off; off >>= 1) s += __shfl_down(s, off);
  if (t == 0) pnorm[x] = s;
}

// ---------------- Kuu fp64 + fp32 copy ----------------
__global__ void k_kuu64(const float* __restrict__ Z, const float* vptr,
                        const float* lptr, double* __restrict__ Kuu64,
                        float* __restrict__ Kuu32) {
  int idx = blockIdx.x * 256 + threadIdx.x;
  if (idx >= G_ * MM_) return;
  int j = idx % M_;
  int r = (idx / M_) % M_;
  int g = idx / MM_;
  const float* zi = Z + (g * M_ + r) * L_;
  const float* zj = Z + (g * M_ + j) * L_;
  double s = 0.0;
  for (int l = 0; l < L_; ++l) {
    double d = (double)zi[l] - (double)zj[l];
    s = fma(d, d, s);
  }
  double v = (double)vptr[0], ls = (double)lptr[0];
  double val = v * exp64(-0.5 * s / (ls * ls));
  if (r == j) val += JITTER_;
  Kuu64[idx] = val;
  Kuu32[idx] = (float)val;
}

// ---------------- 192x192 Gauss-Jordan inverse, 1 barrier/iter (verified) ----------------
__global__ __launch_bounds__(512) void k_inv192(const float* __restrict__ in,
                                                float* __restrict__ out, int gstride) {
  int g = blockIdx.x;
  const float* A = in + (size_t)g * gstride;
  float* O = out + (size_t)g * gstride;
  int t = threadIdx.x;
  int ti = t >> 4, tj = t & 15;
  float a[6][12];
#pragma unroll
  for (int i2 = 0; i2 < 6; ++i2)
#pragma unroll
    for (int j2 = 0; j2 < 12; ++j2)
      a[i2][j2] = A[(ti + 32 * i2) * M_ + (tj + 16 * j2)];

  __shared__ float rowb[2][192], colb[2][192];
  if (ti == 0) {
#pragma unroll
    for (int j2 = 0; j2 < 12; ++j2) rowb[0][tj + 16 * j2] = a[0][j2];
  }
  if (tj == 0) {
#pragma unroll
    for (int i2 = 0; i2 < 6; ++i2) colb[0][ti + 32 * i2] = a[i2][0];
  }
  __syncthreads();

#pragma unroll
  for (int i2k = 0; i2k < 6; ++i2k) {
#pragma unroll
    for (int kh = 0; kh < 2; ++kh) {
      const int j2k = i2k * 2 + kh;
      for (int k2 = 0; k2 < 16; ++k2) {
        const int k = i2k * 32 + kh * 16 + k2;
        const int cur = k & 1, nxt = cur ^ 1;
        const int krow = kh * 16 + k2;
        float p = 1.0f / rowb[cur][k];
        float rv[12];
#pragma unroll
        for (int j2 = 0; j2 < 12; ++j2) rv[j2] = rowb[cur][tj + 16 * j2] * p;
        float cvl[6];
#pragma unroll
        for (int i2 = 0; i2 < 6; ++i2) cvl[i2] = colb[cur][ti + 32 * i2];

        if (k2 < 15) {
          if (ti == krow + 1) {
#pragma unroll
            for (int j2 = 0; j2 < 12; ++j2) {
              float tv = fmaf(-cvl[i2k], rv[j2], a[i2k][j2]);
              if (tj == k2 && j2 == j2k) tv = -cvl[i2k] * p;
              rowb[nxt][tj + 16 * j2] = tv;
            }
          }
          if (tj == k2 + 1) {
#pragma unroll
            for (int i2 = 0; i2 < 6; ++i2) {
              float tv = fmaf(-cvl[i2], rv[j2k], a[i2][j2k]);
              if (ti == krow && i2 == i2k) tv = rv[j2k];
              colb[nxt][ti + 32 * i2] = tv;
            }
          }
        } else if (!(i2k == 5 && kh == 1)) {
          const int i2k1 = (kh == 0) ? i2k : i2k + 1;
          const int krow1 = (kh == 0) ? 16 : 0;
          const int j2k1 = j2k + 1;
          if (ti == krow1) {
#pragma unroll
            for (int j2 = 0; j2 < 12; ++j2) {
              float tv = fmaf(-cvl[i2k1], rv[j2], a[i2k1][j2]);
              if (tj == 15 && j2 == j2k) tv = -cvl[i2k1] * p;
              rowb[nxt][tj + 16 * j2] = tv;
            }
          }
          if (tj == 0) {
#pragma unroll
            for (int i2 = 0; i2 < 6; ++i2) {
              float tv = fmaf(-cvl[i2], rv[j2k1], a[i2][j2k1]);
              if (ti == krow && i2 == i2k) tv = rv[j2k1];
              colb[nxt][ti + 32 * i2] = tv;
            }
          }
        }
        __syncthreads();

#pragma unroll
        for (int i2 = 0; i2 < 6; ++i2)
#pragma unroll
          for (int j2 = 0; j2 < 12; ++j2)
            a[i2][j2] = fmaf(-cvl[i2], rv[j2], a[i2][j2]);
        if (ti == krow) {
#pragma unroll
          for (int j2 = 0; j2 < 12; ++j2) a[i2k][j2] = rv[j2];
        }
        if (tj == k2) {
#pragma unroll
          for (int i2 = 0; i2 < 6; ++i2) a[i2][j2k] = -cvl[i2] * p;
        }
        if (ti == krow && tj == k2) a[i2k][j2k] = p;
      }
    }
  }
#pragma unroll
  for (int i2 = 0; i2 < 6; ++i2)
#pragma unroll
    for (int j2 = 0; j2 < 12; ++j2)
      O[(ti + 32 * i2) * M_ + (tj + 16 * j2)] = a[i2][j2];
}

// ---------------- fp32 tiled GEMM (Schur chain) ----------------
__global__ __launch_bounds__(256) void k_sgemm(
    const float* __restrict__ A, int lda, int tA, int sAg,
    const float* __restrict__ B, int ldb, int tB, int sBg,
    const float* __restrict__ Cin, int sCing, float beta,
    float alpha, int addI,
    float* __restrict__ Cout, int ldc, int sCg,
    float* __restrict__ CoutT, int ldt, int sTg,
    int M, int N, int K) {
  int g = blockIdx.z;
  A += (size_t)g * sAg;
  B += (size_t)g * sBg;
  if (Cin) Cin += (size_t)g * sCing;
  Cout += (size_t)g * sCg;
  if (CoutT) CoutT += (size_t)g * sTg;

  __shared__ float As[32][33], Bs[32][33];
  int t = threadIdx.x;
  int tx = t & 15, ty = t >> 4;
  int row0 = blockIdx.y * 32, col0 = blockIdx.x * 32;
  float acc00 = 0.f, acc01 = 0.f, acc10 = 0.f, acc11 = 0.f;

  for (int kt = 0; kt < K; kt += 32) {
    for (int idx = t; idx < 1024; idx += 256) {
      int rr = idx >> 5, cc = idx & 31;
      {
        int gr = row0 + rr, gk = kt + cc;
        As[rr][cc] = tA ? A[(size_t)gk * lda + gr] : A[(size_t)gr * lda + gk];
      }
      {
        int gk = kt + rr, gc = col0 + cc;
        Bs[rr][cc] = tB ? B[(size_t)gc * ldb + gk] : B[(size_t)gk * ldb + gc];
      }
    }
    __syncthreads();
#pragma unroll
    for (int kk = 0; kk < 32; ++kk) {
      float a0 = As[ty * 2][kk], a1 = As[ty * 2 + 1][kk];
      float b0 = Bs[kk][tx * 2], b1 = Bs[kk][tx * 2 + 1];
      acc00 = fmaf(a0, b0, acc00);
      acc01 = fmaf(a0, b1, acc01);
      acc10 = fmaf(a1, b0, acc10);
      acc11 = fmaf(a1, b1, acc11);
    }
    __syncthreads();
  }
  float accs[2][2] = {{acc00, acc01}, {acc10, acc11}};
#pragma unroll
  for (int a2 = 0; a2 < 2; ++a2)
#pragma unroll
    for (int b2 = 0; b2 < 2; ++b2) {
      int gr = row0 + ty * 2 + a2, gc = col0 + tx * 2 + b2;
      float val = alpha * accs[a2][b2];
      if (addI && gr == gc) val += 1.0f;
      if (Cin) val += beta * Cin[(size_t)gr * ldc + gc];
      Cout[(size_t)gr * ldc + gc] = val;
      if (CoutT) CoutT[(size_t)gc * ldt + gr] = val;
    }
}

// ---------------- mixed-precision fp64-accum GEMM ----------------
__global__ __launch_bounds__(256) void k_dgemmx(
    const void* __restrict__ Ap, int aF64, int lda, int tA, size_t sAg,
    const void* __restrict__ Bp, int bF64, int ldb, int tB, int btril, size_t sBg,
    const void* __restrict__ Cp, int cF64, size_t sCing, double beta,
    double alpha, int addI,
    double* __restrict__ Cout, int ldc, size_t sCg,
    float* __restrict__ f32out,
    int M, int N, int K) {
  int g = blockIdx.z;
  const double* A64 = (const double*)Ap + (size_t)g * sAg;
  const float* A32 = (const float*)Ap + (size_t)g * sAg;
  const double* B64 = (const double*)Bp + (size_t)g * sBg;
  const float* B32 = (const float*)Bp + (size_t)g * sBg;
  const double* C64 = Cp ? (const double*)Cp + (size_t)g * sCing : nullptr;
  const float* C32 = Cp ? (const float*)Cp + (size_t)g * sCing : nullptr;
  if (Cout) Cout += (size_t)g * sCg;
  if (f32out) f32out += (size_t)g * sCg;

  __shared__ double As[32][33], Bs[32][33];
  int t = threadIdx.x;
  int tx = t & 15, ty = t >> 4;
  int row0 = blockIdx.y * 32, col0 = blockIdx.x * 32;
  double acc00 = 0., acc01 = 0., acc10 = 0., acc11 = 0.;

  for (int kt = 0; kt < K; kt += 32) {
    for (int idx = t; idx < 1024; idx += 256) {
      int rr = idx >> 5, cc = idx & 31;
      {
        int gr = row0 + rr, gk = kt + cc;
        size_t ai = tA ? ((size_t)gk * lda + gr) : ((size_t)gr * lda + gk);
        As[rr][cc] = aF64 ? A64[ai] : (double)A32[ai];
      }
      {
        int gk = kt + rr, gc = col0 + cc;
        size_t bi = tB ? ((size_t)gc * ldb + gk) : ((size_t)gk * ldb + gc);
        double bv = bF64 ? B64[bi] : (double)B32[bi];
        if (btril && gc > gk) bv = 0.0;
        Bs[rr][cc] = bv;
      }
    }
    __syncthreads();
#pragma unroll
    for (int kk = 0; kk < 32; ++kk) {
      double a0 = As[ty * 2][kk], a1 = As[ty * 2 + 1][kk];
      double b0 = Bs[kk][tx * 2], b1 = Bs[kk][tx * 2 + 1];
      acc00 = fma(a0, b0, acc00);
      acc01 = fma(a0, b1, acc01);
      acc10 = fma(a1, b0, acc10);
      acc11 = fma(a1, b1, acc11);
    }
    __syncthreads();
  }
  double accs[2][2] = {{acc00, acc01}, {acc10, acc11}};
#pragma unroll
  for (int a2 = 0; a2 < 2; ++a2)
#pragma unroll
    for (int b2 = 0; b2 < 2; ++b2) {
      int gr = row0 + ty * 2 + a2, gc = col0 + tx * 2 + b2;
      double val = alpha * accs[a2][b2];
      if (addI && gr == gc) val += 1.0;
      if (C64) {
        double cv = cF64 ? C64[(size_t)gr * ldc + gc] : (double)C32[(size_t)gr * ldc + gc];
        val += beta * cv;
      }
      if (Cout) Cout[(size_t)gr * ldc + gc] = val;
      if (f32out) f32out[(size_t)gr * ldc + gc] = (float)val;
    }
}

// ---------------- c_g = X * q_mu[:,g] ----------------
__global__ void k_cvec64(const double* __restrict__ X, const float* __restrict__ qmu,
                         float* __restrict__ cvec) {
  int idx = blockIdx.x * 256 + threadIdx.x;
  if (idx >= G_ * M_) return;
  int m = idx % M_, g = idx / M_;
  const double* row = X + (size_t)g * MM_ + (size_t)m * M_;
  double s = 0.0;
  for (int k = 0; k < M_; ++k) s = fma(row[k], (double)qmu[k * G_ + g], s);
  cvec[idx] = (float)s;
}

// ---------------- split S into bf16 hi/lo ----------------
__global__ void k_splitS(const float* __restrict__ Sf, ushortt* __restrict__ Shi,
                         ushortt* __restrict__ Slo) {
  int idx = blockIdx.x * 256 + threadIdx.x;
  if (idx >= G_ * MM_) return;
  float s = Sf[idx];
  ushortt h = f2bf(s);
  Shi[idx] = h;
  Slo[idx] = f2bf(s - bf2f(h));
}

// ---------------- Kuf as GEMM (64x64 tile) -> Kx fp32 + Khi/Klo bf16 ----------------
__global__ __launch_bounds__(256) void k_kufg(const float* __restrict__ pat,
                                              const float* __restrict__ Zt,
                                              const float* __restrict__ znorm,
                                              const float* __restrict__ pnorm,
                                              const float* vptr, const float* lptr,
                                              float* __restrict__ Kx,
                                              ushortt* __restrict__ Khi,
                                              ushortt* __restrict__ Klo,
                                              int x0, int chx) {
  int g = blockIdx.z;
  int col0 = blockIdx.x * 64;
  int row0 = blockIdx.y * 64;
  __shared__ __align__(16) float As[16][68];
  __shared__ __align__(16) float Bs[16][68];
  int t = threadIdx.x;
  int tr = t >> 4, tc = t & 15;
  float acc[4][4] = {};

  for (int kt = 0; kt < LP_; kt += 16) {
    {
      int r = t >> 2, k4 = (t & 3) * 4;
      float4 av = *(const float4*)&pat[(size_t)(x0 + row0 + r) * LP_ + kt + k4];
      As[k4 + 0][r] = av.x;
      As[k4 + 1][r] = av.y;
      As[k4 + 2][r] = av.z;
      As[k4 + 3][r] = av.w;
    }
    {
      int k = t >> 4, c4 = (t & 15) * 4;
      float4 bv = {0.f, 0.f, 0.f, 0.f};
      if (kt + k < L_)
        bv = *(const float4*)&Zt[((size_t)(g * L_ + kt + k)) * M_ + col0 + c4];
      *(float4*)&Bs[k][c4] = bv;
    }
    __syncthreads();
#pragma unroll
    for (int k = 0; k < 16; ++k) {
      float4 av = *(const float4*)&As[k][tr * 4];
      float4 bv = *(const float4*)&Bs[k][tc * 4];
      float a4[4] = {av.x, av.y, av.z, av.w};
      float b4[4] = {bv.x, bv.y, bv.z, bv.w};
#pragma unroll
      for (int i = 0; i < 4; ++i)
#pragma unroll
        for (int j = 0; j < 4; ++j) acc[i][j] = fmaf(a4[i], b4[j], acc[i][j]);
    }
    __syncthreads();
  }
  float v = vptr[0], ls = lptr[0];
  float c2 = -0.72134752044f / (ls * ls);
#pragma unroll
  for (int i = 0; i < 4; ++i) {
    int xl = row0 + tr * 4 + i;
    float pn = pnorm[x0 + xl];
    float tmp[4];
    ushortt hi[4], lo[4];
#pragma unroll
    for (int j = 0; j < 4; ++j) {
      int m = col0 + tc * 4 + j;
      float sq = znorm[g * M_ + m] + pn - 2.0f * acc[i][j];
      tmp[j] = v * exp2f(sq * c2);
      hi[j] = f2bf(tmp[j]);
      lo[j] = f2bf(tmp[j] - bf2f(hi[j]));
    }
    size_t base = ((size_t)g * chx + xl) * M_ + col0 + tc * 4;
    float4 ov = {tmp[0], tmp[1], tmp[2], tmp[3]};
    *(float4*)&Kx[base] = ov;
    *(ushort4*)&Khi[base] = make_ushort4(hi[0], hi[1], hi[2], hi[3]);
    *(ushort4*)&Klo[base] = make_ushort4(lo[0], lo[1], lo[2], lo[3]);
  }
}

// ---------------- LDS frag helper: 16B-aligned read -> short8v ----------------
__device__ __forceinline__ short8v lds_frag(const ushortt* p) {
  int4 v = *(const int4*)p;
  short8v r;
  __builtin_memcpy(&r, &v, 16);
  return r;
}

// ---------------- MFMA U-GEMM + fold, LDS-staged ----------------
// Block 256 = 4 waves. Tile: 128 rows(x) x 128 cols(m'). K-step 32.
// Wave w: rows w*32..w*32+31 (2 row-frags of 16) x all 128 cols (8 col-tiles).
// U = Khi*Shi + Khi*Slo + Klo*Shi (lo*lo dropped). Fragments identical to the
// r11/12-verified convention; sourced from LDS (stride 40 ushorts = 80B -> 16B
// aligned b128 frags). Fold: partial over 128 cols, exact fp32 Kx, atomicAdd.
#define STR_ 40
__global__ __launch_bounds__(256) void k_ufoldm(
    const ushortt* __restrict__ Khi, const ushortt* __restrict__ Klo,
    const float* __restrict__ Kx32,
    const ushortt* __restrict__ Shi, const ushortt* __restrict__ Slo,
    const float* __restrict__ cvec, float* __restrict__ outp,
    int x0, int chx) {
  int g = blockIdx.z;
  int col0 = blockIdx.x * 128;
  int row0 = blockIdx.y * 128;
  const ushortt* Ahg = Khi + (size_t)g * chx * M_;
  const ushortt* Alg = Klo + (size_t)g * chx * M_;
  const float* A32 = Kx32 + (size_t)g * chx * M_;
  const ushortt* Bhg = Shi + (size_t)g * MM_;
  const ushortt* Blg = Slo + (size_t)g * MM_;

  __shared__ __align__(16) ushortt Ahs[128][STR_], Als[128][STR_];
  __shared__ __align__(16) ushortt Bhs[128][STR_], Bls[128][STR_];
  __shared__ float cs[128];

  int t = threadIdx.x;
  if (t < 128) cs[t] = cvec[g * M_ + col0 + t];

  int w = t >> 6, lane = t & 63, n15 = lane & 15, q = lane >> 4;
  int q8 = q * 8;

  // staging map: thread -> (row/col = t>>1, k-half = (t&1)*16)
  int sr = t >> 1, sk = (t & 1) * 16;

  f32x4 acc[2][8];
#pragma unroll
  for (int rf = 0; rf < 2; ++rf)
#pragma unroll
    for (int ct = 0; ct < 8; ++ct) acc[rf][ct] = (f32x4){0.f, 0.f, 0.f, 0.f};

  for (int kt = 0; kt < M_; kt += 32) {
    {
      size_t abase = (size_t)(row0 + sr) * M_ + kt + sk;
      uint4 a0 = *(const uint4*)&Ahg[abase];
      uint4 a1 = *(const uint4*)&Ahg[abase + 8];
      *(uint4*)&Ahs[sr][sk] = a0;
      *(uint4*)&Ahs[sr][sk + 8] = a1;
      uint4 b0 = *(const uint4*)&Alg[abase];
      uint4 b1 = *(const uint4*)&Alg[abase + 8];
      *(uint4*)&Als[sr][sk] = b0;
      *(uint4*)&Als[sr][sk + 8] = b1;
      size_t bbase = (size_t)(col0 + sr) * M_ + kt + sk;
      uint4 c0 = *(const uint4*)&Bhg[bbase];
      uint4 c1 = *(const uint4*)&Bhg[bbase + 8];
      *(uint4*)&Bhs[sr][sk] = c0;
      *(uint4*)&Bhs[sr][sk + 8] = c1;
      uint4 d0 = *(const uint4*)&Blg[bbase];
      uint4 d1 = *(const uint4*)&Blg[bbase + 8];
      *(uint4*)&Bls[sr][sk] = d0;
      *(uint4*)&Bls[sr][sk + 8] = d1;
    }
    __syncthreads();

    short8v ahi0 = lds_frag(&Ahs[w * 32 + n15][q8]);
    short8v ahi1 = lds_frag(&Ahs[w * 32 + 16 + n15][q8]);
    short8v alo0 = lds_frag(&Als[w * 32 + n15][q8]);
    short8v alo1 = lds_frag(&Als[w * 32 + 16 + n15][q8]);
#pragma unroll
    for (int ct = 0; ct < 8; ++ct) {
      short8v bhi = lds_frag(&Bhs[ct * 16 + n15][q8]);
      short8v blo = lds_frag(&Bls[ct * 16 + n15][q8]);
      acc[0][ct] = __builtin_amdgcn_mfma_f32_16x16x32_bf16(ahi0, bhi, acc[0][ct], 0, 0, 0);
      acc[0][ct] = __builtin_amdgcn_mfma_f32_16x16x32_bf16(ahi0, blo, acc[0][ct], 0, 0, 0);
      acc[0][ct] = __builtin_amdgcn_mfma_f32_16x16x32_bf16(alo0, bhi, acc[0][ct], 0, 0, 0);
      acc[1][ct] = __builtin_amdgcn_mfma_f32_16x16x32_bf16(ahi1, bhi, acc[1][ct], 0, 0, 0);
      acc[1][ct] = __builtin_amdgcn_mfma_f32_16x16x32_bf16(ahi1, blo, acc[1][ct], 0, 0, 0);
      acc[1][ct] = __builtin_amdgcn_mfma_f32_16x16x32_bf16(alo1, bhi, acc[1][ct], 0, 0, 0);
    }
    __syncthreads();
  }

  // fold: partial over cols [col0, col0+128). exact fp32 k, fp64 partials, atomics.
#pragma unroll
  for (int rf = 0; rf < 2; ++rf) {
#pragma unroll
    for (int reg = 0; reg < 4; ++reg) {
      int xr2 = row0 + w * 32 + rf * 16 + q * 4 + reg;
      const float* arow = &A32[(size_t)xr2 * M_ + col0];
      double pv = 0.0, pm = 0.0;
#pragma unroll
      for (int ct = 0; ct < 8; ++ct) {
        int col = ct * 16 + n15;
        float kval = arow[col];
        pv += (double)kval * acc[rf][ct][reg];
        pm += (double)kval * cs[col];
      }
#pragma unroll
      for (int mk = 1; mk < 16; mk <<= 1) {
        pv += __shfl_xor(pv, mk, 16);
        pm += __shfl_xor(pm, mk, 16);
      }
      if (n15 == 0) {
        int x = x0 + xr2;
        int p = x >> 5, n = x & 31;
        int oidx = n * (P_ * G_) + p * G_ + g;
        atomicAdd(&outp[oidx], (float)pm);
        atomicAdd(&outp[PN_ * G_ + oidx], (float)pv);
      }
    }
  }
}

extern "C" void kernel_launch(void* const* d_in, const int* in_sizes, int n_in,
                              void* d_out, int out_size, void* d_ws, size_t ws_size,
                              hipStream_t stream) {
  (void)out_size;
  const float* xin = (const float*)d_in[0];
  const float* Z = (const float*)d_in[1];
  const float* qmu = (const float*)d_in[2];
  const float* qsqrt = (const float*)d_in[3];
  const float* vptr = (const float*)d_in[4];
  const float* lptr = (const float*)d_in[5];
  {
    int scalars = 0;
    for (int i = 0; i < n_in; ++i) {
      if (in_sizes[i] == N_ * H_ * W_ * C_) xin = (const float*)d_in[i];
      else if (in_sizes[i] == G_ * M_ * L_) Z = (const float*)d_in[i];
      else if (in_sizes[i] == M_ * G_) qmu = (const float*)d_in[i];
      else if (in_sizes[i] == G_ * MM_) qsqrt = (const float*)d_in[i];
      else if (in_sizes[i] == 1) {
        if (scalars == 0) vptr = (const float*)d_in[i];
        else lptr = (const float*)d_in[i];
        ++scalars;
      }
    }
  }
  float* outp = (float*)d_out;

  auto align256 = [](size_t b) { return (b + 255) & ~(size_t)255; };
  size_t fixed = 0;
  fixed += align256((size_t)G_ * L_ * M_ * 4);      // Zt
  fixed += align256((size_t)G_ * M_ * 4);           // znorm
  fixed += align256((size_t)PN_ * LP_ * 4);         // pat
  fixed += align256((size_t)PN_ * 4);               // pnorm
  fixed += align256((size_t)G_ * MM_ * 4) * 2;      // Kuu32, Kinv32
  fixed += align256((size_t)G_ * 192 * 192 * 4);    // Ebuf
  fixed += align256((size_t)G_ * MM_ * 8) * 3;      // Kuu64, Xd2, Rd
  fixed += align256((size_t)G_ * MM_ * 4);          // Sf
  fixed += align256((size_t)G_ * MM_ * 2) * 2;      // Shi, Slo
  fixed += align256((size_t)G_ * M_ * 4);           // cvec
  size_t kfam = (size_t)G_ * PN_ * M_ * 8;          // Kx fp32 + Khi + Klo per full span
  int nc = 4;
  if (ws_size >= fixed + align256(kfam) + (1u << 20)) nc = 1;
  else if (ws_size >= fixed + align256(kfam / 2) + (1u << 20)) nc = 2;
  int chx = PN_ / nc;   // divisible by 128 for nc in {1,2,4}

  char* w = (char*)d_ws;
  auto alloc = [&](size_t bytes) {
    char* r = w;
    w += (bytes + 255) & ~(size_t)255;
    return r;
  };
  float* Zt      = (float*)alloc((size_t)G_ * L_ * M_ * 4);
  float* znorm   = (float*)alloc((size_t)G_ * M_ * 4);
  float* pat     = (float*)alloc((size_t)PN_ * LP_ * 4);
  float* pnorm   = (float*)alloc((size_t)PN_ * 4);
  float* Kuu32   = (float*)alloc((size_t)G_ * MM_ * 4);
  float* Kinv32  = (float*)alloc((size_t)G_ * MM_ * 4);
  float* Ebuf    = (float*)alloc((size_t)G_ * 192 * 192 * 4);
  double* Kuu64  = (double*)alloc((size_t)G_ * MM_ * 8);
  double* Xd2    = (double*)alloc((size_t)G_ * MM_ * 8);
  double* Rd     = (double*)alloc((size_t)G_ * MM_ * 8);
  float* Sf      = (float*)alloc((size_t)G_ * MM_ * 4);
  ushortt* Shi   = (ushortt*)alloc((size_t)G_ * MM_ * 2);
  ushortt* Slo   = (ushortt*)alloc((size_t)G_ * MM_ * 2);
  float* cvec    = (float*)alloc((size_t)G_ * M_ * 4);
  float* Kx      = (float*)alloc((size_t)G_ * chx * M_ * 4);
  ushortt* Khi   = (ushortt*)alloc((size_t)G_ * chx * M_ * 2);
  ushortt* Klo   = (ushortt*)alloc((size_t)G_ * chx * M_ * 2);

  // ---- prep ----
  k_prep1<<<(G_ * L_ * M_ + 255) / 256, 256, 0, stream>>>(Z, Zt, znorm, outp, vptr);
  k_patchnorm<<<PN_ / 4, 256, 0, stream>>>(xin, pat, pnorm);
  k_kuu64<<<(G_ * MM_ + 255) / 256, 256, 0, stream>>>(Z, vptr, lptr, Kuu64, Kuu32);

  // ---- fp32 seed: Kinv32 via 2x2 block Schur (192+192) ----
  k_inv192<<<G_, 512, 0, stream>>>(Kuu32, Kinv32, MM_);
  k_sgemm<<<dim3(6, 6, G_), 256, 0, stream>>>(
      Kinv32, M_, 0, MM_, Kuu32 + 192, M_, 0, MM_,
      nullptr, 0, 0.0f, 1.0f, 0,
      Ebuf, 192, 192 * 192, nullptr, 0, 0, 192, 192, 192);
  k_sgemm<<<dim3(6, 6, G_), 256, 0, stream>>>(
      Kuu32 + 192, M_, 1, MM_, Ebuf, 192, 0, 192 * 192,
      Kuu32 + 192 * M_ + 192, MM_, 1.0f, -1.0f, 0,
      Kuu32 + 192 * M_ + 192, M_, MM_, nullptr, 0, 0, 192, 192, 192);
  k_inv192<<<G_, 512, 0, stream>>>(Kuu32 + 192 * M_ + 192, Kinv32 + 192 * M_ + 192, MM_);
  k_sgemm<<<dim3(6, 6, G_), 256, 0, stream>>>(
      Ebuf, 192, 0, 192 * 192, Kinv32 + 192 * M_ + 192, M_, 0, MM_,
      nullptr, 0, 0.0f, -1.0f, 0,
      Kinv32 + 192, M_, MM_, Kinv32 + 192 * M_, M_, MM_, 192, 192, 192);
  k_sgemm<<<dim3(6, 6, G_), 256, 0, stream>>>(
      Kinv32 + 192, M_, 0, MM_, Ebuf, 192, 1, 192 * 192,
      Kinv32, MM_, 1.0f, -1.0f, 0,
      Kinv32, M_, MM_, nullptr, 0, 0, 192, 192, 192);

  // ---- one fp64 Newton step: X2 = X0 + X0(I - Kuu X0) ----
  k_dgemmx<<<dim3(12, 12, G_), 256, 0, stream>>>(
      Kuu64, 1, M_, 0, (size_t)MM_,
      Kinv32, 0, M_, 0, 0, (size_t)MM_,
      nullptr, 0, 0, 0.0,
      -1.0, 1, Rd, M_, (size_t)MM_, nullptr, M_, M_, M_);
  k_dgemmx<<<dim3(12, 12, G_), 256, 0, stream>>>(
      Kinv32, 0, M_, 0, (size_t)MM_,
      Rd, 1, M_, 0, 0, (size_t)MM_,
      Kinv32, 0, (size_t)MM_, 1.0,
      1.0, 0, Xd2, M_, (size_t)MM_, nullptr, M_, M_, M_);

  // ---- S = (X Lq)(X Lq)^T - X -> Sf fp32 -> bf16 hi/lo ; c = X q_mu ----
  k_dgemmx<<<dim3(12, 12, G_), 256, 0, stream>>>(
      Xd2, 1, M_, 0, (size_t)MM_,
      qsqrt, 0, M_, 0, 1, (size_t)MM_,
      nullptr, 0, 0, 0.0,
      1.0, 0, Rd, M_, (size_t)MM_, nullptr, M_, M_, M_);      // Rd = V
  k_dgemmx<<<dim3(12, 12, G_), 256, 0, stream>>>(
      Rd, 1, M_, 0, (size_t)MM_,
      Rd, 1, M_, 1, 0, (size_t)MM_,
      Xd2, 1, (size_t)MM_, -1.0,
      1.0, 0, nullptr, M_, (size_t)MM_, Sf, M_, M_, M_);       // Sf = V V^T - X
  k_splitS<<<(G_ * MM_ + 255) / 256, 256, 0, stream>>>(Sf, Shi, Slo);
  k_cvec64<<<(G_ * M_ + 255) / 256, 256, 0, stream>>>(Xd2, qmu, cvec);

  // ---- per-chunk: K build (fp32 + bf16 hi/lo), LDS-staged MFMA U-GEMM + fold ----
  for (int ch = 0; ch < nc; ++ch) {
    int x0 = ch * chx;
    k_kufg<<<dim3(M_ / 64, chx / 64, G_), 256, 0, stream>>>(
        pat, Zt, znorm, pnorm, vptr, lptr, Kx, Khi, Klo, x0, chx);
    k_ufoldm<<<dim3(M_ / 128, chx / 128, G_), 256, 0, stream>>>(
        Khi, Klo, Kx, Shi, Slo, cvec, outp, x0, chx);
  }
}